// Round 2
// baseline (818.684 us; speedup 1.0000x reference)
//
#include <hip/hip_runtime.h>
#include <math.h>

// GATConv (PyG 1.3.2), H=1, IN=C=128. 3 dispatches:
//  k1 wtzero: W -> bf16 W^T (padded) + zero gcur
//  k2 gemm_scatter: heterogeneous grid — blocks [0,sb): bucket-scatter (LDS stash);
//                   blocks [sb,sb+gb): MFMA bf16 gemm, x-tile LDS-staged (coalesced),
//                   2 row-tiles per block (128 rows)
//  k3 aggregate: SORT-FREE edge-parallel bucket aggregation:
//                phase A: per-edge p=exp(leaky(alpha)) (no max shift; alpha bounded),
//                         ssum via LDS f32 atomics, pack (dst|srcByteOff) in LDS;
//                phase C: 4 edges per dwordx4 instr (16 lanes/edge, full 256B row),
//                         scale + ds_add_f32 into out_lds[64][132] (padded stride);
//                phase D: normalize + bias, coalesced float4 store.
//                No counting sort, no per-node padding, loads pipeline freely
//                (ds_add is fire-and-forget).

constexpr int CH = 128;
constexpr int BNODES = 64;     // dst nodes per bucket
constexpr int CAP = 2048;      // max edges per bucket (avg ~1088, >25 sigma headroom)
constexpr int NBMAX = 1024;    // supports N <= 65536
constexpr int SCHUNK = 4096;   // edges per scatter block
constexpr int WTS = 136;       // padded row stride in bf16 (16B-aligned; b128 reads uniform)
constexpr int OSTR = 132;      // out_lds row stride in floats (132%32=4 -> bank spread, 16B-aligned)

typedef __attribute__((ext_vector_type(8))) short bf16x8;
typedef __attribute__((ext_vector_type(4))) float f32x4;

static __device__ __forceinline__ unsigned short f2bf(float f) {
    unsigned u = __float_as_uint(f);
    unsigned r = (u + 0x7fffu + ((u >> 16) & 1u)) >> 16;   // RNE
    return (unsigned short)r;
}

// W[128][128] fp32 -> WT[n][k] bf16 (stride WTS) + zero gcur. Grid 8 x 256.
__global__ __launch_bounds__(256) void wtzero_kernel(const float* __restrict__ W,
                                                     unsigned short* __restrict__ WT,
                                                     int* __restrict__ gcur, int nb) {
    const int T = blockIdx.x * 256 + threadIdx.x;   // 0..2047
    if (T < nb) gcur[T] = 0;
    const int k = T >> 4;
    const int n8 = (T & 15) * 8;
    const float4 a = *(const float4*)&W[k * CH + n8];
    const float4 b = *(const float4*)&W[k * CH + n8 + 4];
    WT[(n8 + 0) * WTS + k] = f2bf(a.x);
    WT[(n8 + 1) * WTS + k] = f2bf(a.y);
    WT[(n8 + 2) * WTS + k] = f2bf(a.z);
    WT[(n8 + 3) * WTS + k] = f2bf(a.w);
    WT[(n8 + 4) * WTS + k] = f2bf(b.x);
    WT[(n8 + 5) * WTS + k] = f2bf(b.y);
    WT[(n8 + 6) * WTS + k] = f2bf(b.z);
    WT[(n8 + 7) * WTS + k] = f2bf(b.w);
}

// Heterogeneous: blocks [0,sb) scatter, [sb,sb+gb) gemm (2x64-row tiles). 256 thr.
__global__ __launch_bounds__(256) void gemm_scatter_kernel(const float* __restrict__ x,
                                                           const unsigned short* __restrict__ WT,
                                                           const float* __restrict__ att,
                                                           unsigned short* __restrict__ hb,
                                                           float* __restrict__ ad,
                                                           float* __restrict__ as_,
                                                           const int* __restrict__ src,
                                                           const int* __restrict__ dst,
                                                           int* __restrict__ gcur,
                                                           unsigned* __restrict__ recs,
                                                           int n, int etot, int nb, int sb) {
    __shared__ alignas(16) unsigned char smem[52224];   // WT 34816 + Xs 17408
    const int tid = threadIdx.x;

    if ((int)blockIdx.x >= sb) {
        // ------- GEMM branch: 128 rows = 2 x-tiles; WT + x-tile staged in LDS -------
        unsigned short* Wl = (unsigned short*)smem;                  // 34816 B
        unsigned short* Xs = (unsigned short*)(smem + 34816);        // 64 x WTS bf16
        {
            const uint4* s = (const uint4*)WT;
            uint4* d = (uint4*)Wl;
            for (int i = tid; i < CH * WTS / 8; i += 256) d[i] = s[i];
        }

        const int lane = tid & 63, wave = tid >> 6;
        const int m = lane & 15, quad = lane >> 4;
        const int tbase = ((int)blockIdx.x - sb) * 128;
        // x staging map: 4 threads per row, interleaved float4s (coalesced 64B/4thr)
        const int srow = tid >> 2, sseg = tid & 3;

        #pragma unroll 1
        for (int half = 0; half < 2; ++half) {
            __syncthreads();   // protect Xs (and cover initial Wl stage)
            {
                const int grow = min(tbase + half * 64 + srow, n - 1);
                const float* gx = x + (size_t)grow * CH;
                unsigned short* xd = &Xs[srow * WTS];
                #pragma unroll
                for (int i = 0; i < 8; ++i) {
                    const int c = sseg * 4 + i * 16;
                    const float4 u = *(const float4*)&gx[c];
                    ushort4 hs;
                    hs.x = f2bf(u.x); hs.y = f2bf(u.y); hs.z = f2bf(u.z); hs.w = f2bf(u.w);
                    *(ushort4*)&xd[c] = hs;
                }
            }
            __syncthreads();

            const int row0 = tbase + half * 64 + wave * 16;
            f32x4 acc[8] = {};
            #pragma unroll
            for (int t = 0; t < 4; ++t) {
                const int kb = t * 32 + quad * 8;
                const bf16x8 afr = *(const bf16x8*)&Xs[(wave * 16 + m) * WTS + kb];
                #pragma unroll
                for (int nt = 0; nt < 8; ++nt) {
                    const bf16x8 bfr = *(const bf16x8*)&Wl[(nt * 16 + m) * WTS + kb];
                    acc[nt] = __builtin_amdgcn_mfma_f32_16x16x32_bf16(afr, bfr, acc[nt], 0, 0, 0);
                }
            }

            const int rbase = row0 + quad * 4;
            float pd[4] = {}, ps[4] = {};
            #pragma unroll
            for (int nt = 0; nt < 8; ++nt) {
                const int col = nt * 16 + m;
                const float atd = att[col], ats = att[CH + col];
                #pragma unroll
                for (int r = 0; r < 4; ++r) {
                    pd[r] = fmaf(acc[nt][r], atd, pd[r]);
                    ps[r] = fmaf(acc[nt][r], ats, ps[r]);
                    const int rr = rbase + r;
                    if (rr < n) hb[(size_t)rr * CH + col] = f2bf(acc[nt][r]);
                }
            }
            #pragma unroll
            for (int r = 0; r < 4; ++r) {
                #pragma unroll
                for (int off = 8; off >= 1; off >>= 1) {
                    pd[r] += __shfl_xor(pd[r], off, 64);
                    ps[r] += __shfl_xor(ps[r], off, 64);
                }
                const int rr = rbase + r;
                if (m == 0 && rr < n) { ad[rr] = pd[r]; as_[rr] = ps[r]; }
            }
        }
    } else {
        // ------- SCATTER branch: bin SCHUNK edges into buckets (LDS stash) -------
        int* hist = (int*)smem;                       // 4096 B
        int* cur = hist + NBMAX;                      // 4096 B
        unsigned* rbuf = (unsigned*)(cur + NBMAX);    // 16384 B
        const int e0 = (int)blockIdx.x * SCHUNK;
        for (int t = tid; t < nb; t += 256) hist[t] = 0;
        __syncthreads();
        for (int i = tid; i < SCHUNK; i += 256) {
            const int e = e0 + i;
            if (e < etot) {
                const int d = dst[e];
                rbuf[i] = ((unsigned)d << 16) | (unsigned)src[e];
                atomicAdd(&hist[d >> 6], 1);
            }
        }
        __syncthreads();
        for (int t = tid; t < nb; t += 256) {
            const int h = hist[t];
            cur[t] = h ? atomicAdd(&gcur[t], h) : 0;   // reserve contiguous range
        }
        __syncthreads();
        for (int i = tid; i < SCHUNK; i += 256) {
            const int e = e0 + i;
            if (e < etot) {
                const unsigned r = rbuf[i];
                const int d = (int)(r >> 16);
                const int b = d >> 6;
                const int pos = atomicAdd(&cur[b], 1);
                if (pos < CAP)
                    recs[(size_t)b * CAP + pos] = ((unsigned)(d & 63) << 16) | (r & 0xffffu);
            }
        }
    }
}

// One 512-thread block per bucket. Sort-free edge-parallel aggregation.
__global__ __launch_bounds__(512) void aggregate_kernel(const unsigned char* __restrict__ hwb,
                                                        const float* __restrict__ ad,
                                                        const float* __restrict__ as_,
                                                        const int* __restrict__ gcur,
                                                        const unsigned* __restrict__ recs,
                                                        const float* __restrict__ bias,
                                                        float* __restrict__ out, int n) {
    __shared__ alignas(16) float out_lds[BNODES * OSTR];   // 33792 B
    __shared__ alignas(16) float pl[CAP + 4];              // 8208 B
    __shared__ alignas(16) unsigned pack[CAP + 4];         // 8208 B
    __shared__ float ssumL[BNODES];
    __shared__ float adl[BNODES];
    const int b = blockIdx.x;
    const int tid = threadIdx.x, lane = tid & 63, wid = tid >> 6;
    const unsigned* br = recs + (size_t)b * CAP;
    int nE = gcur[b]; if (nE > CAP) nE = CAP;

    // ---- init: zero out_lds (float4), init ssum/adl ----
    {
        float4* oz = (float4*)out_lds;
        for (int i = tid; i < BNODES * OSTR / 4; i += 512) oz[i] = float4{0.f, 0.f, 0.f, 0.f};
        if (tid < BNODES) {
            ssumL[tid] = 0.f;
            const int node = b * BNODES + tid;
            adl[tid] = (node < n) ? ad[node] : 0.f;
        }
    }
    __syncthreads();

    // ---- phase A: p = exp(leaky_relu(ad[dst]+as[src])); ssum; pack dst|srcByteOff ----
    for (int i = tid; i < nE; i += 512) {
        const unsigned r = br[i];
        const int d = (int)(r >> 16);          // 0..63
        const unsigned s = r & 0xffffu;        // src node id
        float a = adl[d] + as_[s];
        a = (a >= 0.f) ? a : 0.2f * a;
        const float p = __expf(a);
        atomicAdd(&ssumL[d], p);
        pl[i] = p;
        pack[i] = ((unsigned)d << 26) | (s << 8);   // dst[6] | src*256 (byte offset)
    }
    if (tid < 4) { pl[nE + tid] = 0.f; pack[nE + tid] = 0u; }   // pad to x4
    __syncthreads();

    // ---- phase C: edge-parallel gather. 4 edges per dwordx4 (16 lanes/edge). ----
    {
        const int q = lane >> 4;                   // which edge of the group
        const int m16 = lane & 15;                 // 16B segment within the 256B row
        const unsigned coff = (unsigned)m16 * 16u;
        const int ngp = (nE + 3) >> 2;
        #pragma unroll 4
        for (int gi = wid; gi < ngp; gi += 8) {
            const int e = gi * 4 + q;
            const unsigned pk = pack[e];           // 4 distinct LDS addrs, 16-lane bcast
            const float p = pl[e];
            const uint4 g = *(const uint4*)(hwb + (pk & 0x00FFFF00u) + coff);
            float* orow = &out_lds[(pk >> 26) * OSTR + m16 * 8];
            atomicAdd(&orow[0], p * __uint_as_float(g.x << 16));
            atomicAdd(&orow[1], p * __uint_as_float(g.x & 0xffff0000u));
            atomicAdd(&orow[2], p * __uint_as_float(g.y << 16));
            atomicAdd(&orow[3], p * __uint_as_float(g.y & 0xffff0000u));
            atomicAdd(&orow[4], p * __uint_as_float(g.z << 16));
            atomicAdd(&orow[5], p * __uint_as_float(g.z & 0xffff0000u));
            atomicAdd(&orow[6], p * __uint_as_float(g.w << 16));
            atomicAdd(&orow[7], p * __uint_as_float(g.w & 0xffff0000u));
        }
    }
    __syncthreads();

    // ---- phase D: normalize + bias, coalesced float4 stores (32 thr/node row) ----
    for (int i = tid; i < BNODES * (CH / 4); i += 512) {
        const int ln = i >> 5;                 // node within bucket
        const int c4 = i & 31;                 // float4 index within row
        const int node = b * BNODES + ln;
        if (node >= n) continue;
        const float inv = 1.f / (ssumL[ln] + 1e-16f);
        const float4 v = *(const float4*)&out_lds[ln * OSTR + c4 * 4];
        const float4 bv = *(const float4*)&bias[c4 * 4];
        float4 o;
        o.x = fmaf(v.x, inv, bv.x);
        o.y = fmaf(v.y, inv, bv.y);
        o.z = fmaf(v.z, inv, bv.z);
        o.w = fmaf(v.w, inv, bv.w);
        *(float4*)&out[(size_t)node * CH + c4 * 4] = o;
    }
}

extern "C" void kernel_launch(void* const* d_in, const int* in_sizes, int n_in,
                              void* d_out, int out_size, void* d_ws, size_t ws_size,
                              hipStream_t stream) {
    const float* x    = (const float*)d_in[0];
    const int*   ei   = (const int*)d_in[1];
    const float* W    = (const float*)d_in[2];
    const float* att  = (const float*)d_in[3];
    const float* bias = (const float*)d_in[4];
    float* out = (float*)d_out;

    const int N_   = in_sizes[0] / CH;   // 50000
    const int Etot = in_sizes[1] / 2;    // 850000
    const int* src = ei;
    const int* dst = ei + Etot;
    const int nb = (N_ + BNODES - 1) / BNODES;        // 782
    const int gb = (N_ + 127) / 128;                  // 391 gemm blocks
    const int sb = (Etot + SCHUNK - 1) / SCHUNK;      // 208 scatter blocks

    char* ws = (char*)d_ws;
    size_t off = 0;
    auto alloc = [&](size_t bytes) -> void* {
        void* p = ws + off;
        off = (off + bytes + 255) & ~(size_t)255;
        return p;
    };
    unsigned short* hb = (unsigned short*)alloc((size_t)N_ * CH * sizeof(unsigned short));
    unsigned short* WT = (unsigned short*)alloc((size_t)CH * WTS * sizeof(unsigned short));
    float* ad      = (float*)alloc((size_t)N_ * sizeof(float));
    float* as_     = (float*)alloc((size_t)N_ * sizeof(float));
    int*   gcur    = (int*)  alloc((size_t)nb * sizeof(int));
    unsigned* recs = (unsigned*)alloc((size_t)nb * CAP * sizeof(unsigned));
    (void)ws_size; (void)n_in; (void)out_size;

    wtzero_kernel<<<8, 256, 0, stream>>>(W, WT, gcur, nb);
    gemm_scatter_kernel<<<sb + gb, 256, 0, stream>>>(x, WT, att, hb, ad, as_,
                                                     src, dst, gcur, recs, N_, Etot, nb, sb);
    aggregate_kernel<<<nb, 512, 0, stream>>>((const unsigned char*)hb, ad, as_, gcur, recs, bias, out, N_);
}

// Round 3
// 328.744 us; speedup vs baseline: 2.4903x; 2.4903x over previous
//
#include <hip/hip_runtime.h>
#include <hip/hip_cooperative_groups.h>
#include <math.h>

namespace cg = cooperative_groups;

// GATConv (PyG 1.3.2), H=1, IN=C=128.
// SINGLE cooperative dispatch (3-dispatch fallback if coop launch refused):
//  P0: W -> bf16 W^T (padded) + zero gcur            (blocks 0..7)
//  P1: heterogeneous — items [0,sb): bucket-scatter; [sb,sb+gb): MFMA gemm
//  P2: per-bucket counting sort + 16-deep gather (round-0 proven structure,
//      4 waves/bucket, grid-strided)
// grid.sync() + __threadfence() between phases (cross-XCD visibility).

constexpr int CH = 128;
constexpr int BNODES = 64;     // dst nodes per bucket
constexpr int CAP = 2048;      // max edges per bucket (avg ~1088)
constexpr int SCAP = 3072;     // CAP + 64*16 pad headroom
constexpr int NBMAX = 1024;    // supports N <= 65536
constexpr int SCHUNK = 4096;   // edges per scatter block
constexpr int WTS = 136;       // padded row stride in bf16
constexpr unsigned SENT = 0xFFFFFFFFu;

typedef __attribute__((ext_vector_type(8))) short bf16x8;
typedef __attribute__((ext_vector_type(4))) float f32x4;

static __device__ __forceinline__ unsigned short f2bf(float f) {
    unsigned u = __float_as_uint(f);
    unsigned r = (u + 0x7fffu + ((u >> 16) & 1u)) >> 16;   // RNE
    return (unsigned short)r;
}

// ============================ fused cooperative kernel ============================
__global__ __launch_bounds__(256) void fused_kernel(
    const float* __restrict__ x, const float* __restrict__ W,
    const float* __restrict__ att, const float* __restrict__ bias,
    const int* __restrict__ src, const int* __restrict__ dst,
    unsigned short* __restrict__ WT, unsigned short* __restrict__ hb,
    float* __restrict__ ad, float* __restrict__ as_,
    int* __restrict__ gcur, unsigned* __restrict__ recs,
    float* __restrict__ out,
    int n, int etot, int nb, int sb, int gb)
{
    __shared__ alignas(16) unsigned char smem[52224];
    const int tid = threadIdx.x;
    cg::grid_group grid = cg::this_grid();

    // ---------------- P0: WT build + gcur zero (blocks 0..7) ----------------
    {
        const int T = (int)blockIdx.x * 256 + tid;
        if (T < 2048) {
            if (T < nb) gcur[T] = 0;
            const int k = T >> 4;
            const int n8 = (T & 15) * 8;
            const float4 a = *(const float4*)&W[k * CH + n8];
            const float4 bq = *(const float4*)&W[k * CH + n8 + 4];
            WT[(n8 + 0) * WTS + k] = f2bf(a.x);
            WT[(n8 + 1) * WTS + k] = f2bf(a.y);
            WT[(n8 + 2) * WTS + k] = f2bf(a.z);
            WT[(n8 + 3) * WTS + k] = f2bf(a.w);
            WT[(n8 + 4) * WTS + k] = f2bf(bq.x);
            WT[(n8 + 5) * WTS + k] = f2bf(bq.y);
            WT[(n8 + 6) * WTS + k] = f2bf(bq.z);
            WT[(n8 + 7) * WTS + k] = f2bf(bq.w);
        }
    }
    __threadfence();
    grid.sync();
    __threadfence();

    // ---------------- P1: scatter + gemm (grid-stride over items) ----------------
    for (int item = (int)blockIdx.x; item < sb + gb; item += (int)gridDim.x) {
        __syncthreads();   // protect smem across items
        if (item >= sb) {
            // ------- GEMM: 128 rows = 2 x-tiles; WT + x-tile staged in LDS -------
            unsigned short* Wl = (unsigned short*)smem;                  // 34816 B
            unsigned short* Xs = (unsigned short*)(smem + 34816);        // 64 x WTS
            {
                const uint4* s = (const uint4*)WT;
                uint4* d = (uint4*)Wl;
                for (int i = tid; i < CH * WTS / 8; i += 256) d[i] = s[i];
            }
            const int lane = tid & 63, wave = tid >> 6;
            const int m = lane & 15, quad = lane >> 4;
            const int tbase = (item - sb) * 128;
            const int srow = tid >> 2, sseg = tid & 3;

            #pragma unroll 1
            for (int half = 0; half < 2; ++half) {
                __syncthreads();   // protect Xs (covers Wl stage on first pass)
                {
                    const int grow = min(tbase + half * 64 + srow, n - 1);
                    const float* gx = x + (size_t)grow * CH;
                    unsigned short* xd = &Xs[srow * WTS];
                    #pragma unroll
                    for (int i = 0; i < 8; ++i) {
                        const int c = sseg * 4 + i * 16;
                        const float4 u = *(const float4*)&gx[c];
                        ushort4 hs;
                        hs.x = f2bf(u.x); hs.y = f2bf(u.y); hs.z = f2bf(u.z); hs.w = f2bf(u.w);
                        *(ushort4*)&xd[c] = hs;
                    }
                }
                __syncthreads();

                const int row0 = tbase + half * 64 + wave * 16;
                f32x4 acc[8] = {};
                #pragma unroll
                for (int t = 0; t < 4; ++t) {
                    const int kb = t * 32 + quad * 8;
                    const bf16x8 afr = *(const bf16x8*)&Xs[(wave * 16 + m) * WTS + kb];
                    #pragma unroll
                    for (int nt = 0; nt < 8; ++nt) {
                        const bf16x8 bfr = *(const bf16x8*)&Wl[(nt * 16 + m) * WTS + kb];
                        acc[nt] = __builtin_amdgcn_mfma_f32_16x16x32_bf16(afr, bfr, acc[nt], 0, 0, 0);
                    }
                }

                const int rbase = row0 + quad * 4;
                float pd[4] = {}, ps[4] = {};
                #pragma unroll
                for (int nt = 0; nt < 8; ++nt) {
                    const int col = nt * 16 + m;
                    const float atd = att[col], ats = att[CH + col];
                    #pragma unroll
                    for (int r = 0; r < 4; ++r) {
                        pd[r] = fmaf(acc[nt][r], atd, pd[r]);
                        ps[r] = fmaf(acc[nt][r], ats, ps[r]);
                        const int rr = rbase + r;
                        if (rr < n) hb[(size_t)rr * CH + col] = f2bf(acc[nt][r]);
                    }
                }
                #pragma unroll
                for (int r = 0; r < 4; ++r) {
                    #pragma unroll
                    for (int off = 8; off >= 1; off >>= 1) {
                        pd[r] += __shfl_xor(pd[r], off, 64);
                        ps[r] += __shfl_xor(ps[r], off, 64);
                    }
                    const int rr = rbase + r;
                    if (m == 0 && rr < n) { ad[rr] = pd[r]; as_[rr] = ps[r]; }
                }
            }
        } else {
            // ------- SCATTER: bin SCHUNK edges into buckets (LDS stash) -------
            int* hist = (int*)smem;                       // 4096 B
            int* curh = hist + NBMAX;                     // 4096 B
            unsigned* rbuf = (unsigned*)(curh + NBMAX);   // 16384 B
            const int e0 = item * SCHUNK;
            for (int t = tid; t < nb; t += 256) hist[t] = 0;
            __syncthreads();
            for (int i = tid; i < SCHUNK; i += 256) {
                const int e = e0 + i;
                if (e < etot) {
                    const int d = dst[e];
                    rbuf[i] = ((unsigned)d << 16) | (unsigned)src[e];
                    atomicAdd(&hist[d >> 6], 1);
                }
            }
            __syncthreads();
            for (int t = tid; t < nb; t += 256) {
                const int h = hist[t];
                curh[t] = h ? atomicAdd(&gcur[t], h) : 0;
            }
            __syncthreads();
            for (int i = tid; i < SCHUNK; i += 256) {
                const int e = e0 + i;
                if (e < etot) {
                    const unsigned r = rbuf[i];
                    const int d = (int)(r >> 16);
                    const int bk = d >> 6;
                    const int pos = atomicAdd(&curh[bk], 1);
                    if (pos < CAP)
                        recs[(size_t)bk * CAP + pos] = ((unsigned)(d & 63) << 16) | (r & 0xffffu);
                }
            }
        }
    }
    __threadfence();
    grid.sync();
    __threadfence();

    // ---------------- P2: aggregate (grid-stride over buckets, 4 waves) ----------------
    {
        const unsigned char* hwb = (const unsigned char*)hb;
        unsigned* sorted = (unsigned*)smem;                // 12288 B
        float* alphas    = (float*)(smem + 12288);         // 12288 B
        float* adl       = (float*)(smem + 24576);         // 256 B
        int* cnt         = (int*)(smem + 24832);           // 256 B
        int* ofs         = (int*)(smem + 25088);           // 256 B
        int* curq        = (int*)(smem + 25344);           // 256 B
        int* nEp_s       = (int*)(smem + 25600);           // 4 B
        const int lane = tid & 63, wid = tid >> 6;
        const unsigned lane4 = (unsigned)lane * 4u;

        for (int b = (int)blockIdx.x; b < nb; b += (int)gridDim.x) {
            __syncthreads();   // protect smem across buckets
            const unsigned* br = recs + (size_t)b * CAP;
            int nE = gcur[b]; if (nE > CAP) nE = CAP;
            unsigned* stash = (unsigned*)alphas;

            if (tid < BNODES) {
                cnt[tid] = 0;
                const int node = b * BNODES + tid;
                adl[tid] = (node < n) ? ad[node] : 0.f;
            }
            __syncthreads();
            for (int i = tid; i < nE; i += 256) {
                const unsigned r = br[i];
                stash[i] = r;
                atomicAdd(&cnt[r >> 16], 1);
            }
            __syncthreads();
            if (wid == 0) {                       // exclusive scan of x16-rounded counts
                const int c = cnt[lane];
                const int cr = (c + 15) & ~15;
                int v = cr;
                #pragma unroll
                for (int off = 1; off < 64; off <<= 1) {
                    const int u = __shfl_up(v, (unsigned)off, 64);
                    if (lane >= off) v += u;
                }
                ofs[lane] = v - cr;
                curq[lane] = v - cr;
                if (lane == 63) *nEp_s = v;
            }
            __syncthreads();
            const int nEp = *nEp_s;
            for (int i = tid; i < nEp; i += 256) sorted[i] = SENT;
            __syncthreads();
            for (int i = tid; i < nE; i += 256) {
                const unsigned r = stash[i];
                const int pos = atomicAdd(&curq[r >> 16], 1);
                sorted[pos] = r;
            }
            __syncthreads();
            for (int i = tid; i < nEp; i += 256) {   // overwrites stash
                const unsigned r = sorted[i];
                float p = 0.f;
                unsigned so = 0u;
                if (r != SENT) {
                    float a = adl[r >> 16] + as_[r & 0xffffu];
                    a = (a >= 0.f) ? a : 0.2f * a;
                    p = __expf(a);
                    so = (r & 0xffffu) << 8;
                }
                alphas[i] = p;
                sorted[i] = so;
            }
            __syncthreads();

            for (int ln = wid; ln < BNODES; ln += 4) {
                const int node = b * BNODES + ln;
                if (node >= n) break;
                const int start = ofs[ln];
                const int endp = start + ((cnt[ln] + 15) & ~15);

                float ssum = 0.f, acc0 = 0.f, acc1 = 0.f;
                for (int e = start; e < endp; e += 16) {
                    const uint4 s0 = *(const uint4*)&sorted[e];
                    const uint4 s1 = *(const uint4*)&sorted[e + 4];
                    const uint4 s2 = *(const uint4*)&sorted[e + 8];
                    const uint4 s3 = *(const uint4*)&sorted[e + 12];
                    const float4 p0 = *(const float4*)&alphas[e];
                    const float4 p1 = *(const float4*)&alphas[e + 4];
                    const float4 p2 = *(const float4*)&alphas[e + 8];
                    const float4 p3 = *(const float4*)&alphas[e + 12];
                    unsigned g[16];
                    g[0]  = *(const unsigned*)(hwb + (s0.x + lane4));
                    g[1]  = *(const unsigned*)(hwb + (s0.y + lane4));
                    g[2]  = *(const unsigned*)(hwb + (s0.z + lane4));
                    g[3]  = *(const unsigned*)(hwb + (s0.w + lane4));
                    g[4]  = *(const unsigned*)(hwb + (s1.x + lane4));
                    g[5]  = *(const unsigned*)(hwb + (s1.y + lane4));
                    g[6]  = *(const unsigned*)(hwb + (s1.z + lane4));
                    g[7]  = *(const unsigned*)(hwb + (s1.w + lane4));
                    g[8]  = *(const unsigned*)(hwb + (s2.x + lane4));
                    g[9]  = *(const unsigned*)(hwb + (s2.y + lane4));
                    g[10] = *(const unsigned*)(hwb + (s2.z + lane4));
                    g[11] = *(const unsigned*)(hwb + (s2.w + lane4));
                    g[12] = *(const unsigned*)(hwb + (s3.x + lane4));
                    g[13] = *(const unsigned*)(hwb + (s3.y + lane4));
                    g[14] = *(const unsigned*)(hwb + (s3.z + lane4));
                    g[15] = *(const unsigned*)(hwb + (s3.w + lane4));
                    ssum += (p0.x + p0.y + p0.z + p0.w) + (p1.x + p1.y + p1.z + p1.w)
                          + (p2.x + p2.y + p2.z + p2.w) + (p3.x + p3.y + p3.z + p3.w);
                    const float p[16] = {p0.x, p0.y, p0.z, p0.w, p1.x, p1.y, p1.z, p1.w,
                                         p2.x, p2.y, p2.z, p2.w, p3.x, p3.y, p3.z, p3.w};
                    #pragma unroll
                    for (int j = 0; j < 16; ++j) {
                        acc0 = fmaf(p[j], __uint_as_float((g[j] & 0xffffu) << 16), acc0);
                        acc1 = fmaf(p[j], __uint_as_float(g[j] & 0xffff0000u), acc1);
                    }
                }
                const float inv = 1.f / (ssum + 1e-16f);
                const float2 bv = *(const float2*)&bias[lane * 2];
                float2 o;
                o.x = fmaf(acc0, inv, bv.x);
                o.y = fmaf(acc1, inv, bv.y);
                *(float2*)&out[(size_t)node * CH + lane * 2] = o;
            }
        }
    }
}

// ============================ fallback kernels (round-0) ============================
__global__ __launch_bounds__(256) void wtzero_kernel(const float* __restrict__ W,
                                                     unsigned short* __restrict__ WT,
                                                     int* __restrict__ gcur, int nb) {
    const int T = blockIdx.x * 256 + threadIdx.x;
    if (T < nb) gcur[T] = 0;
    const int k = T >> 4;
    const int n8 = (T & 15) * 8;
    const float4 a = *(const float4*)&W[k * CH + n8];
    const float4 b = *(const float4*)&W[k * CH + n8 + 4];
    WT[(n8 + 0) * WTS + k] = f2bf(a.x);
    WT[(n8 + 1) * WTS + k] = f2bf(a.y);
    WT[(n8 + 2) * WTS + k] = f2bf(a.z);
    WT[(n8 + 3) * WTS + k] = f2bf(a.w);
    WT[(n8 + 4) * WTS + k] = f2bf(b.x);
    WT[(n8 + 5) * WTS + k] = f2bf(b.y);
    WT[(n8 + 6) * WTS + k] = f2bf(b.z);
    WT[(n8 + 7) * WTS + k] = f2bf(b.w);
}

__global__ __launch_bounds__(256) void gemm_scatter_kernel(const float* __restrict__ x,
                                                           const unsigned short* __restrict__ WT,
                                                           const float* __restrict__ att,
                                                           unsigned short* __restrict__ hb,
                                                           float* __restrict__ ad,
                                                           float* __restrict__ as_,
                                                           const int* __restrict__ src,
                                                           const int* __restrict__ dst,
                                                           int* __restrict__ gcur,
                                                           unsigned* __restrict__ recs,
                                                           int n, int etot, int nb, int sb) {
    __shared__ alignas(16) unsigned char smem[52224];
    const int tid = threadIdx.x;

    if ((int)blockIdx.x >= sb) {
        unsigned short* Wl = (unsigned short*)smem;
        unsigned short* Xs = (unsigned short*)(smem + 34816);
        {
            const uint4* s = (const uint4*)WT;
            uint4* d = (uint4*)Wl;
            for (int i = tid; i < CH * WTS / 8; i += 256) d[i] = s[i];
        }
        const int lane = tid & 63, wave = tid >> 6;
        const int m = lane & 15, quad = lane >> 4;
        const int tbase = ((int)blockIdx.x - sb) * 128;
        const int srow = tid >> 2, sseg = tid & 3;

        #pragma unroll 1
        for (int half = 0; half < 2; ++half) {
            __syncthreads();
            {
                const int grow = min(tbase + half * 64 + srow, n - 1);
                const float* gx = x + (size_t)grow * CH;
                unsigned short* xd = &Xs[srow * WTS];
                #pragma unroll
                for (int i = 0; i < 8; ++i) {
                    const int c = sseg * 4 + i * 16;
                    const float4 u = *(const float4*)&gx[c];
                    ushort4 hs;
                    hs.x = f2bf(u.x); hs.y = f2bf(u.y); hs.z = f2bf(u.z); hs.w = f2bf(u.w);
                    *(ushort4*)&xd[c] = hs;
                }
            }
            __syncthreads();

            const int row0 = tbase + half * 64 + wave * 16;
            f32x4 acc[8] = {};
            #pragma unroll
            for (int t = 0; t < 4; ++t) {
                const int kb = t * 32 + quad * 8;
                const bf16x8 afr = *(const bf16x8*)&Xs[(wave * 16 + m) * WTS + kb];
                #pragma unroll
                for (int nt = 0; nt < 8; ++nt) {
                    const bf16x8 bfr = *(const bf16x8*)&Wl[(nt * 16 + m) * WTS + kb];
                    acc[nt] = __builtin_amdgcn_mfma_f32_16x16x32_bf16(afr, bfr, acc[nt], 0, 0, 0);
                }
            }

            const int rbase = row0 + quad * 4;
            float pd[4] = {}, ps[4] = {};
            #pragma unroll
            for (int nt = 0; nt < 8; ++nt) {
                const int col = nt * 16 + m;
                const float atd = att[col], ats = att[CH + col];
                #pragma unroll
                for (int r = 0; r < 4; ++r) {
                    pd[r] = fmaf(acc[nt][r], atd, pd[r]);
                    ps[r] = fmaf(acc[nt][r], ats, ps[r]);
                    const int rr = rbase + r;
                    if (rr < n) hb[(size_t)rr * CH + col] = f2bf(acc[nt][r]);
                }
            }
            #pragma unroll
            for (int r = 0; r < 4; ++r) {
                #pragma unroll
                for (int off = 8; off >= 1; off >>= 1) {
                    pd[r] += __shfl_xor(pd[r], off, 64);
                    ps[r] += __shfl_xor(ps[r], off, 64);
                }
                const int rr = rbase + r;
                if (m == 0 && rr < n) { ad[rr] = pd[r]; as_[rr] = ps[r]; }
            }
        }
    } else {
        int* hist = (int*)smem;
        int* cur = hist + NBMAX;
        unsigned* rbuf = (unsigned*)(cur + NBMAX);
        const int e0 = (int)blockIdx.x * SCHUNK;
        for (int t = tid; t < nb; t += 256) hist[t] = 0;
        __syncthreads();
        for (int i = tid; i < SCHUNK; i += 256) {
            const int e = e0 + i;
            if (e < etot) {
                const int d = dst[e];
                rbuf[i] = ((unsigned)d << 16) | (unsigned)src[e];
                atomicAdd(&hist[d >> 6], 1);
            }
        }
        __syncthreads();
        for (int t = tid; t < nb; t += 256) {
            const int h = hist[t];
            cur[t] = h ? atomicAdd(&gcur[t], h) : 0;
        }
        __syncthreads();
        for (int i = tid; i < SCHUNK; i += 256) {
            const int e = e0 + i;
            if (e < etot) {
                const unsigned r = rbuf[i];
                const int d = (int)(r >> 16);
                const int b = d >> 6;
                const int pos = atomicAdd(&cur[b], 1);
                if (pos < CAP)
                    recs[(size_t)b * CAP + pos] = ((unsigned)(d & 63) << 16) | (r & 0xffffu);
            }
        }
    }
}

__global__ __launch_bounds__(512) void aggregate_kernel(const unsigned char* __restrict__ hwb,
                                                        const float* __restrict__ ad,
                                                        const float* __restrict__ as_,
                                                        const int* __restrict__ gcur,
                                                        const unsigned* __restrict__ recs,
                                                        const float* __restrict__ bias,
                                                        float* __restrict__ out, int n) {
    __shared__ alignas(16) unsigned sorted[SCAP];
    __shared__ alignas(16) float alphas[SCAP];
    __shared__ float adl[BNODES];
    __shared__ int cnt[BNODES], ofs[BNODES], cur[BNODES];
    __shared__ int nEp_s;
    const int b = blockIdx.x;
    const int tid = threadIdx.x, lane = tid & 63, wid = tid >> 6;
    const unsigned* br = recs + (size_t)b * CAP;
    int nE = gcur[b]; if (nE > CAP) nE = CAP;
    unsigned* stash = (unsigned*)alphas;

    if (tid < BNODES) {
        cnt[tid] = 0;
        const int node = b * BNODES + tid;
        adl[tid] = (node < n) ? ad[node] : 0.f;
    }
    __syncthreads();
    for (int i = tid; i < nE; i += 512) {
        const unsigned r = br[i];
        stash[i] = r;
        atomicAdd(&cnt[r >> 16], 1);
    }
    __syncthreads();
    if (wid == 0) {
        const int c = cnt[lane];
        const int cr = (c + 15) & ~15;
        int v = cr;
        #pragma unroll
        for (int off = 1; off < 64; off <<= 1) {
            const int u = __shfl_up(v, (unsigned)off, 64);
            if (lane >= off) v += u;
        }
        ofs[lane] = v - cr;
        cur[lane] = v - cr;
        if (lane == 63) nEp_s = v;
    }
    __syncthreads();
    const int nEp = nEp_s;
    for (int i = tid; i < nEp; i += 512) sorted[i] = SENT;
    __syncthreads();
    for (int i = tid; i < nE; i += 512) {
        const unsigned r = stash[i];
        const int pos = atomicAdd(&cur[r >> 16], 1);
        sorted[pos] = r;
    }
    __syncthreads();
    for (int i = tid; i < nEp; i += 512) {
        const unsigned r = sorted[i];
        float p = 0.f;
        unsigned so = 0u;
        if (r != SENT) {
            float a = adl[r >> 16] + as_[r & 0xffffu];
            a = (a >= 0.f) ? a : 0.2f * a;
            p = __expf(a);
            so = (r & 0xffffu) << 8;
        }
        alphas[i] = p;
        sorted[i] = so;
    }
    __syncthreads();

    const unsigned lane4 = (unsigned)lane * 4u;
    for (int ln = wid; ln < BNODES; ln += 8) {
        const int node = b * BNODES + ln;
        if (node >= n) break;
        const int start = ofs[ln];
        const int endp = start + ((cnt[ln] + 15) & ~15);

        float ssum = 0.f, acc0 = 0.f, acc1 = 0.f;
        for (int e = start; e < endp; e += 16) {
            const uint4 s0 = *(const uint4*)&sorted[e];
            const uint4 s1 = *(const uint4*)&sorted[e + 4];
            const uint4 s2 = *(const uint4*)&sorted[e + 8];
            const uint4 s3 = *(const uint4*)&sorted[e + 12];
            const float4 p0 = *(const float4*)&alphas[e];
            const float4 p1 = *(const float4*)&alphas[e + 4];
            const float4 p2 = *(const float4*)&alphas[e + 8];
            const float4 p3 = *(const float4*)&alphas[e + 12];
            unsigned g[16];
            g[0]  = *(const unsigned*)(hwb + (s0.x + lane4));
            g[1]  = *(const unsigned*)(hwb + (s0.y + lane4));
            g[2]  = *(const unsigned*)(hwb + (s0.z + lane4));
            g[3]  = *(const unsigned*)(hwb + (s0.w + lane4));
            g[4]  = *(const unsigned*)(hwb + (s1.x + lane4));
            g[5]  = *(const unsigned*)(hwb + (s1.y + lane4));
            g[6]  = *(const unsigned*)(hwb + (s1.z + lane4));
            g[7]  = *(const unsigned*)(hwb + (s1.w + lane4));
            g[8]  = *(const unsigned*)(hwb + (s2.x + lane4));
            g[9]  = *(const unsigned*)(hwb + (s2.y + lane4));
            g[10] = *(const unsigned*)(hwb + (s2.z + lane4));
            g[11] = *(const unsigned*)(hwb + (s2.w + lane4));
            g[12] = *(const unsigned*)(hwb + (s3.x + lane4));
            g[13] = *(const unsigned*)(hwb + (s3.y + lane4));
            g[14] = *(const unsigned*)(hwb + (s3.z + lane4));
            g[15] = *(const unsigned*)(hwb + (s3.w + lane4));
            ssum += (p0.x + p0.y + p0.z + p0.w) + (p1.x + p1.y + p1.z + p1.w)
                  + (p2.x + p2.y + p2.z + p2.w) + (p3.x + p3.y + p3.z + p3.w);
            const float p[16] = {p0.x, p0.y, p0.z, p0.w, p1.x, p1.y, p1.z, p1.w,
                                 p2.x, p2.y, p2.z, p2.w, p3.x, p3.y, p3.z, p3.w};
            #pragma unroll
            for (int j = 0; j < 16; ++j) {
                acc0 = fmaf(p[j], __uint_as_float((g[j] & 0xffffu) << 16), acc0);
                acc1 = fmaf(p[j], __uint_as_float(g[j] & 0xffff0000u), acc1);
            }
        }
        const float inv = 1.f / (ssum + 1e-16f);
        const float2 bv = *(const float2*)&bias[lane * 2];
        float2 o;
        o.x = fmaf(acc0, inv, bv.x);
        o.y = fmaf(acc1, inv, bv.y);
        *(float2*)&out[node * CH + lane * 2] = o;
    }
}

extern "C" void kernel_launch(void* const* d_in, const int* in_sizes, int n_in,
                              void* d_out, int out_size, void* d_ws, size_t ws_size,
                              hipStream_t stream) {
    const float* x    = (const float*)d_in[0];
    const int*   ei   = (const int*)d_in[1];
    const float* W    = (const float*)d_in[2];
    const float* att  = (const float*)d_in[3];
    const float* bias = (const float*)d_in[4];
    float* out = (float*)d_out;

    int N_   = in_sizes[0] / CH;   // 50000
    int Etot = in_sizes[1] / 2;    // 850000
    const int* src = ei;
    const int* dst = ei + Etot;
    int nb = (N_ + BNODES - 1) / BNODES;        // 782
    int gb = (N_ + 127) / 128;                  // 391 gemm items
    int sb = (Etot + SCHUNK - 1) / SCHUNK;      // 208 scatter items

    char* ws = (char*)d_ws;
    size_t off = 0;
    auto alloc = [&](size_t bytes) -> void* {
        void* p = ws + off;
        off = (off + bytes + 255) & ~(size_t)255;
        return p;
    };
    unsigned short* hb = (unsigned short*)alloc((size_t)N_ * CH * sizeof(unsigned short));
    unsigned short* WT = (unsigned short*)alloc((size_t)CH * WTS * sizeof(unsigned short));
    float* ad      = (float*)alloc((size_t)N_ * sizeof(float));
    float* as_     = (float*)alloc((size_t)N_ * sizeof(float));
    int*   gcur    = (int*)  alloc((size_t)nb * sizeof(int));
    unsigned* recs = (unsigned*)alloc((size_t)nb * CAP * sizeof(unsigned));
    (void)ws_size; (void)n_in; (void)out_size;

    // ---- cooperative capacity query (host-side, cached; graph-capture safe) ----
    static int coopBlocks = -1;    // -1 unknown, 0 unsupported
    if (coopBlocks == -1) {
        int bpc = 0;
        if (hipOccupancyMaxActiveBlocksPerMultiprocessor(&bpc, fused_kernel, 256, 0) == hipSuccess
            && bpc > 0) {
            int dev = 0;
            hipGetDevice(&dev);
            hipDeviceProp_t prop;
            int ncu = 256;
            if (hipGetDeviceProperties(&prop, dev) == hipSuccess && prop.multiProcessorCount > 0)
                ncu = prop.multiProcessorCount;
            coopBlocks = bpc * ncu;
        } else {
            coopBlocks = 0;
        }
    }

    bool launched = false;
    if (coopBlocks > 0) {
        int need = sb + gb;               // P1 items
        if (nb > need) need = nb;         // P2 buckets
        if (need < 8) need = 8;           // P0 coverage
        int grid = coopBlocks < need ? coopBlocks : need;
        void* args[] = {
            (void*)&x, (void*)&W, (void*)&att, (void*)&bias,
            (void*)&src, (void*)&dst,
            (void*)&WT, (void*)&hb, (void*)&ad, (void*)&as_,
            (void*)&gcur, (void*)&recs, (void*)&out,
            (void*)&N_, (void*)&Etot, (void*)&nb, (void*)&sb, (void*)&gb
        };
        if (hipLaunchCooperativeKernel(fused_kernel, dim3(grid), dim3(256),
                                       args, 0, stream) == hipSuccess) {
            launched = true;
        } else {
            coopBlocks = 0;   // don't retry
        }
    }

    if (!launched) {
        wtzero_kernel<<<8, 256, 0, stream>>>(W, WT, gcur, nb);
        gemm_scatter_kernel<<<sb + gb, 256, 0, stream>>>(x, WT, att, hb, ad, as_,
                                                         src, dst, gcur, recs, N_, Etot, nb, sb);
        aggregate_kernel<<<nb, 512, 0, stream>>>((const unsigned char*)hb, ad, as_,
                                                 gcur, recs, bias, out, N_);
    }
}

// Round 4
// 135.389 us; speedup vs baseline: 6.0469x; 2.4282x over previous
//
#include <hip/hip_runtime.h>
#include <math.h>

// GATConv (PyG 1.3.2), H=1, IN=C=128. memset + 2 dispatches:
//  memset: gcur = 0 (tiny stream-ordered node)
//  k2 gemm_scatter: heterogeneous grid — blocks [0,sb): bucket-scatter (LDS stash);
//                   blocks [sb,sb+gb): MFMA bf16 gemm. W^T built in-LDS per block
//                   from W directly (no separate wtzero kernel, no global WT).
//  k3 aggregate: per-bucket LDS counting sort; p=exp(leaky(alpha)) without max-shift
//                (alpha bounded, softmax invariant to common factor); 16-deep gather.
//                (round-0 proven structure, 512 thr, 8 waves/bucket)

constexpr int CH = 128;
constexpr int BNODES = 64;     // dst nodes per bucket
constexpr int CAP = 2048;      // max edges per bucket (avg ~1088)
constexpr int SCAP = 3072;     // CAP + 64*15 pad headroom (3008 max)
constexpr int NBMAX = 1024;    // supports N <= 65536
constexpr int SCHUNK = 4096;   // edges per scatter block
constexpr int WTS = 136;       // padded row stride in bf16 (16B-aligned; b128 reads uniform)
constexpr unsigned SENT = 0xFFFFFFFFu;

typedef __attribute__((ext_vector_type(8))) short bf16x8;
typedef __attribute__((ext_vector_type(4))) float f32x4;

static __device__ __forceinline__ unsigned short f2bf(float f) {
    unsigned u = __float_as_uint(f);
    unsigned r = (u + 0x7fffu + ((u >> 16) & 1u)) >> 16;   // RNE
    return (unsigned short)r;
}

// Heterogeneous: blocks [0,sb) scatter, [sb,sb+gb) gemm (2x64-row tiles). 256 thr.
__global__ __launch_bounds__(256) void gemm_scatter_kernel(const float* __restrict__ x,
                                                           const float* __restrict__ W,
                                                           const float* __restrict__ att,
                                                           unsigned short* __restrict__ hb,
                                                           float* __restrict__ ad,
                                                           float* __restrict__ as_,
                                                           const int* __restrict__ src,
                                                           const int* __restrict__ dst,
                                                           int* __restrict__ gcur,
                                                           unsigned* __restrict__ recs,
                                                           int n, int etot, int nb, int sb) {
    __shared__ alignas(16) unsigned char smem[52224];   // Wl 34816 + Xs 17408
    const int tid = threadIdx.x;

    if ((int)blockIdx.x >= sb) {
        // ------- GEMM branch: 128 rows = 2 x-tiles; Wl built in-LDS from W -------
        unsigned short* Wl = (unsigned short*)smem;                  // 34816 B
        unsigned short* Xs = (unsigned short*)(smem + 34816);        // 64 x WTS bf16
        {
            // thread owns k-quad kb4 (4 rows of W) x n-group nb16 (16 cols);
            // writes 16 transposed ushort4 columns into Wl[n][k].
            const int kb4 = tid >> 3;       // 0..31
            const int nb16 = tid & 7;       // 0..7
            const float* wp = W + (size_t)(kb4 * 4) * CH + nb16 * 16;
            const float4 r0a = *(const float4*)(wp + 0);
            const float4 r0b = *(const float4*)(wp + 4);
            const float4 r0c = *(const float4*)(wp + 8);
            const float4 r0d = *(const float4*)(wp + 12);
            const float4 r1a = *(const float4*)(wp + CH + 0);
            const float4 r1b = *(const float4*)(wp + CH + 4);
            const float4 r1c = *(const float4*)(wp + CH + 8);
            const float4 r1d = *(const float4*)(wp + CH + 12);
            const float4 r2a = *(const float4*)(wp + 2 * CH + 0);
            const float4 r2b = *(const float4*)(wp + 2 * CH + 4);
            const float4 r2c = *(const float4*)(wp + 2 * CH + 8);
            const float4 r2d = *(const float4*)(wp + 2 * CH + 12);
            const float4 r3a = *(const float4*)(wp + 3 * CH + 0);
            const float4 r3b = *(const float4*)(wp + 3 * CH + 4);
            const float4 r3c = *(const float4*)(wp + 3 * CH + 8);
            const float4 r3d = *(const float4*)(wp + 3 * CH + 12);
            unsigned short* wl = Wl + (nb16 * 16) * WTS + kb4 * 4;
            #define WRC(c, f0, f1, f2, f3) { ushort4 t_;                         \
                t_.x = f2bf(f0); t_.y = f2bf(f1); t_.z = f2bf(f2); t_.w = f2bf(f3); \
                *(ushort4*)&wl[(c) * WTS] = t_; }
            WRC(0,  r0a.x, r1a.x, r2a.x, r3a.x)
            WRC(1,  r0a.y, r1a.y, r2a.y, r3a.y)
            WRC(2,  r0a.z, r1a.z, r2a.z, r3a.z)
            WRC(3,  r0a.w, r1a.w, r2a.w, r3a.w)
            WRC(4,  r0b.x, r1b.x, r2b.x, r3b.x)
            WRC(5,  r0b.y, r1b.y, r2b.y, r3b.y)
            WRC(6,  r0b.z, r1b.z, r2b.z, r3b.z)
            WRC(7,  r0b.w, r1b.w, r2b.w, r3b.w)
            WRC(8,  r0c.x, r1c.x, r2c.x, r3c.x)
            WRC(9,  r0c.y, r1c.y, r2c.y, r3c.y)
            WRC(10, r0c.z, r1c.z, r2c.z, r3c.z)
            WRC(11, r0c.w, r1c.w, r2c.w, r3c.w)
            WRC(12, r0d.x, r1d.x, r2d.x, r3d.x)
            WRC(13, r0d.y, r1d.y, r2d.y, r3d.y)
            WRC(14, r0d.z, r1d.z, r2d.z, r3d.z)
            WRC(15, r0d.w, r1d.w, r2d.w, r3d.w)
            #undef WRC
        }

        const int lane = tid & 63, wave = tid >> 6;
        const int m = lane & 15, quad = lane >> 4;
        const int tbase = ((int)blockIdx.x - sb) * 128;
        // x staging map: 4 threads per row, interleaved float4s (coalesced 64B/4thr)
        const int srow = tid >> 2, sseg = tid & 3;

        #pragma unroll 1
        for (int half = 0; half < 2; ++half) {
            __syncthreads();   // protect Xs (and cover Wl build on first pass)
            {
                const int grow = min(tbase + half * 64 + srow, n - 1);
                const float* gx = x + (size_t)grow * CH;
                unsigned short* xd = &Xs[srow * WTS];
                #pragma unroll
                for (int i = 0; i < 8; ++i) {
                    const int c = sseg * 4 + i * 16;
                    const float4 u = *(const float4*)&gx[c];
                    ushort4 hs;
                    hs.x = f2bf(u.x); hs.y = f2bf(u.y); hs.z = f2bf(u.z); hs.w = f2bf(u.w);
                    *(ushort4*)&xd[c] = hs;
                }
            }
            __syncthreads();

            const int row0 = tbase + half * 64 + wave * 16;
            f32x4 acc[8] = {};
            #pragma unroll
            for (int t = 0; t < 4; ++t) {
                const int kb = t * 32 + quad * 8;
                const bf16x8 afr = *(const bf16x8*)&Xs[(wave * 16 + m) * WTS + kb];
                #pragma unroll
                for (int nt = 0; nt < 8; ++nt) {
                    const bf16x8 bfr = *(const bf16x8*)&Wl[(nt * 16 + m) * WTS + kb];
                    acc[nt] = __builtin_amdgcn_mfma_f32_16x16x32_bf16(afr, bfr, acc[nt], 0, 0, 0);
                }
            }

            const int rbase = row0 + quad * 4;
            float pd[4] = {}, ps[4] = {};
            #pragma unroll
            for (int nt = 0; nt < 8; ++nt) {
                const int col = nt * 16 + m;
                const float atd = att[col], ats = att[CH + col];
                #pragma unroll
                for (int r = 0; r < 4; ++r) {
                    pd[r] = fmaf(acc[nt][r], atd, pd[r]);
                    ps[r] = fmaf(acc[nt][r], ats, ps[r]);
                    const int rr = rbase + r;
                    if (rr < n) hb[(size_t)rr * CH + col] = f2bf(acc[nt][r]);
                }
            }
            #pragma unroll
            for (int r = 0; r < 4; ++r) {
                #pragma unroll
                for (int off = 8; off >= 1; off >>= 1) {
                    pd[r] += __shfl_xor(pd[r], off, 64);
                    ps[r] += __shfl_xor(ps[r], off, 64);
                }
                const int rr = rbase + r;
                if (m == 0 && rr < n) { ad[rr] = pd[r]; as_[rr] = ps[r]; }
            }
        }
    } else {
        // ------- SCATTER branch: bin SCHUNK edges into buckets (LDS stash) -------
        int* hist = (int*)smem;                       // 4096 B
        int* cur = hist + NBMAX;                      // 4096 B
        unsigned* rbuf = (unsigned*)(cur + NBMAX);    // 16384 B
        const int e0 = (int)blockIdx.x * SCHUNK;
        for (int t = tid; t < nb; t += 256) hist[t] = 0;
        __syncthreads();
        for (int i = tid; i < SCHUNK; i += 256) {
            const int e = e0 + i;
            if (e < etot) {
                const int d = dst[e];
                rbuf[i] = ((unsigned)d << 16) | (unsigned)src[e];
                atomicAdd(&hist[d >> 6], 1);
            }
        }
        __syncthreads();
        for (int t = tid; t < nb; t += 256) {
            const int h = hist[t];
            cur[t] = h ? atomicAdd(&gcur[t], h) : 0;   // reserve contiguous range
        }
        __syncthreads();
        for (int i = tid; i < SCHUNK; i += 256) {
            const int e = e0 + i;
            if (e < etot) {
                const unsigned r = rbuf[i];
                const int d = (int)(r >> 16);
                const int b = d >> 6;
                const int pos = atomicAdd(&cur[b], 1);
                if (pos < CAP)
                    recs[(size_t)b * CAP + pos] = ((unsigned)(d & 63) << 16) | (r & 0xffffu);
            }
        }
    }
}

// One 512-thread block per bucket. stash+hist -> scan(x16 pad) -> sort -> p=exp(leaky)
// -> per-wave single-node gather, 16 loads in flight, ssum in-loop (lane-broadcast).
__global__ __launch_bounds__(512) void aggregate_kernel(const unsigned char* __restrict__ hwb,
                                                        const float* __restrict__ ad,
                                                        const float* __restrict__ as_,
                                                        const int* __restrict__ gcur,
                                                        const unsigned* __restrict__ recs,
                                                        const float* __restrict__ bias,
                                                        float* __restrict__ out, int n) {
    __shared__ alignas(16) unsigned sorted[SCAP];
    __shared__ alignas(16) float alphas[SCAP];
    __shared__ float adl[BNODES];
    __shared__ int cnt[BNODES], ofs[BNODES], cur[BNODES];
    __shared__ int nEp_s;
    const int b = blockIdx.x;
    const int tid = threadIdx.x, lane = tid & 63, wid = tid >> 6;
    const unsigned* br = recs + (size_t)b * CAP;
    int nE = gcur[b]; if (nE > CAP) nE = CAP;
    unsigned* stash = (unsigned*)alphas;

    if (tid < BNODES) {
        cnt[tid] = 0;
        const int node = b * BNODES + tid;
        adl[tid] = (node < n) ? ad[node] : 0.f;
    }
    __syncthreads();
    for (int i = tid; i < nE; i += 512) {
        const unsigned r = br[i];
        stash[i] = r;
        atomicAdd(&cnt[r >> 16], 1);
    }
    __syncthreads();
    if (wid == 0) {                       // exclusive scan of x16-rounded counts
        const int c = cnt[lane];
        const int cr = (c + 15) & ~15;
        int v = cr;
        #pragma unroll
        for (int off = 1; off < 64; off <<= 1) {
            const int u = __shfl_up(v, (unsigned)off, 64);
            if (lane >= off) v += u;
        }
        ofs[lane] = v - cr;
        cur[lane] = v - cr;
        if (lane == 63) nEp_s = v;
    }
    __syncthreads();
    const int nEp = nEp_s;
    for (int i = tid; i < nEp; i += 512) sorted[i] = SENT;
    __syncthreads();
    for (int i = tid; i < nE; i += 512) {
        const unsigned r = stash[i];
        const int pos = atomicAdd(&cur[r >> 16], 1);
        sorted[pos] = r;
    }
    __syncthreads();
    // p = exp(leaky_relu(ad[dst]+as[src])); rec -> h byte-offset (src*256); pad p=0.
    for (int i = tid; i < nEp; i += 512) {   // overwrites stash
        const unsigned r = sorted[i];
        float p = 0.f;
        unsigned so = 0u;
        if (r != SENT) {
            float a = adl[r >> 16] + as_[r & 0xffffu];
            a = (a >= 0.f) ? a : 0.2f * a;
            p = __expf(a);
            so = (r & 0xffffu) << 8;
        }
        alphas[i] = p;
        sorted[i] = so;
    }
    __syncthreads();

    const unsigned lane4 = (unsigned)lane * 4u;
    for (int ln = wid; ln < BNODES; ln += 8) {
        const int node = b * BNODES + ln;
        if (node >= n) break;
        const int start = ofs[ln];
        const int endp = start + ((cnt[ln] + 15) & ~15);

        float ssum = 0.f, acc0 = 0.f, acc1 = 0.f;
        for (int e = start; e < endp; e += 16) {
            const uint4 s0 = *(const uint4*)&sorted[e];
            const uint4 s1 = *(const uint4*)&sorted[e + 4];
            const uint4 s2 = *(const uint4*)&sorted[e + 8];
            const uint4 s3 = *(const uint4*)&sorted[e + 12];
            const float4 p0 = *(const float4*)&alphas[e];
            const float4 p1 = *(const float4*)&alphas[e + 4];
            const float4 p2 = *(const float4*)&alphas[e + 8];
            const float4 p3 = *(const float4*)&alphas[e + 12];
            unsigned g[16];
            g[0]  = *(const unsigned*)(hwb + (s0.x + lane4));
            g[1]  = *(const unsigned*)(hwb + (s0.y + lane4));
            g[2]  = *(const unsigned*)(hwb + (s0.z + lane4));
            g[3]  = *(const unsigned*)(hwb + (s0.w + lane4));
            g[4]  = *(const unsigned*)(hwb + (s1.x + lane4));
            g[5]  = *(const unsigned*)(hwb + (s1.y + lane4));
            g[6]  = *(const unsigned*)(hwb + (s1.z + lane4));
            g[7]  = *(const unsigned*)(hwb + (s1.w + lane4));
            g[8]  = *(const unsigned*)(hwb + (s2.x + lane4));
            g[9]  = *(const unsigned*)(hwb + (s2.y + lane4));
            g[10] = *(const unsigned*)(hwb + (s2.z + lane4));
            g[11] = *(const unsigned*)(hwb + (s2.w + lane4));
            g[12] = *(const unsigned*)(hwb + (s3.x + lane4));
            g[13] = *(const unsigned*)(hwb + (s3.y + lane4));
            g[14] = *(const unsigned*)(hwb + (s3.z + lane4));
            g[15] = *(const unsigned*)(hwb + (s3.w + lane4));
            ssum += (p0.x + p0.y + p0.z + p0.w) + (p1.x + p1.y + p1.z + p1.w)
                  + (p2.x + p2.y + p2.z + p2.w) + (p3.x + p3.y + p3.z + p3.w);
            const float p[16] = {p0.x, p0.y, p0.z, p0.w, p1.x, p1.y, p1.z, p1.w,
                                 p2.x, p2.y, p2.z, p2.w, p3.x, p3.y, p3.z, p3.w};
            #pragma unroll
            for (int j = 0; j < 16; ++j) {
                acc0 = fmaf(p[j], __uint_as_float((g[j] & 0xffffu) << 16), acc0);
                acc1 = fmaf(p[j], __uint_as_float(g[j] & 0xffff0000u), acc1);
            }
        }
        const float inv = 1.f / (ssum + 1e-16f);
        const float2 bv = *(const float2*)&bias[lane * 2];
        float2 o;
        o.x = fmaf(acc0, inv, bv.x);
        o.y = fmaf(acc1, inv, bv.y);
        *(float2*)&out[node * CH + lane * 2] = o;
    }
}

extern "C" void kernel_launch(void* const* d_in, const int* in_sizes, int n_in,
                              void* d_out, int out_size, void* d_ws, size_t ws_size,
                              hipStream_t stream) {
    const float* x    = (const float*)d_in[0];
    const int*   ei   = (const int*)d_in[1];
    const float* W    = (const float*)d_in[2];
    const float* att  = (const float*)d_in[3];
    const float* bias = (const float*)d_in[4];
    float* out = (float*)d_out;

    const int N_   = in_sizes[0] / CH;   // 50000
    const int Etot = in_sizes[1] / 2;    // 850000
    const int* src = ei;
    const int* dst = ei + Etot;
    const int nb = (N_ + BNODES - 1) / BNODES;        // 782
    const int gb = (N_ + 127) / 128;                  // 391 gemm blocks
    const int sb = (Etot + SCHUNK - 1) / SCHUNK;      // 208 scatter blocks

    char* ws = (char*)d_ws;
    size_t off = 0;
    auto alloc = [&](size_t bytes) -> void* {
        void* p = ws + off;
        off = (off + bytes + 255) & ~(size_t)255;
        return p;
    };
    unsigned short* hb = (unsigned short*)alloc((size_t)N_ * CH * sizeof(unsigned short));
    float* ad      = (float*)alloc((size_t)N_ * sizeof(float));
    float* as_     = (float*)alloc((size_t)N_ * sizeof(float));
    int*   gcur    = (int*)  alloc((size_t)nb * sizeof(int));
    unsigned* recs = (unsigned*)alloc((size_t)nb * CAP * sizeof(unsigned));
    (void)ws_size; (void)n_in; (void)out_size;

    hipMemsetAsync(gcur, 0, (size_t)nb * sizeof(int), stream);
    gemm_scatter_kernel<<<sb + gb, 256, 0, stream>>>(x, W, att, hb, ad, as_,
                                                     src, dst, gcur, recs, N_, Etot, nb, sb);
    aggregate_kernel<<<nb, 512, 0, stream>>>((const unsigned char*)hb, ad, as_, gcur, recs, bias, out, N_);
}